// Round 1
// baseline (494.707 us; speedup 1.0000x reference)
//
#include <hip/hip_runtime.h>

// LengthRegulator: B=64, C=384, T=512 -> MAX_NEW_TIME=4096
// dur[b,t] in [0,8). csum = inclusive scan. Frame t owns output positions
// [csum[t-1], csum[t]). Positions >= total are zero. Mask = (out[b,0,j] != 0).

#define BB 64
#define CC 384
#define TT 512
#define TOUT 4096

// Kernel 1: per-batch scan of durations + scatter of frame index into idx table.
// idx[b*TOUT + j] = t such that csum[t-1] <= j < csum[t], else -1.
__global__ __launch_bounds__(TT) void build_idx_kernel(
    const int* __restrict__ dur, int* __restrict__ idx) {
  const int b = blockIdx.x;
  const int t = threadIdx.x;

  __shared__ int s[TT];
  const int d = dur[b * TT + t];
  s[t] = d;
  __syncthreads();

  // Hillis-Steele inclusive scan over 512 elements (9 steps)
  for (int off = 1; off < TT; off <<= 1) {
    int v = (t >= off) ? s[t - off] : 0;
    __syncthreads();
    s[t] += v;
    __syncthreads();
  }

  const int end = s[t];
  const int start = end - d;

  int* __restrict__ idxb = idx + b * TOUT;
  // Fill with -1 (invalid / zero region)
  #pragma unroll
  for (int k = 0; k < TOUT / TT; ++k) idxb[t + k * TT] = -1;
  __syncthreads();

  // Scatter: segments are disjoint, at most 7 writes per thread
  for (int p = start; p < end; ++p) idxb[p] = t;
}

// Kernel 2: coalesced float4 expand-gather.
// grid = (TOUT/1024, C, B), block = 256, 4 floats per thread.
__global__ __launch_bounds__(256) void gather_kernel(
    const float* __restrict__ x, const int* __restrict__ idx,
    float* __restrict__ out, float* __restrict__ mask) {
  const int b = blockIdx.z;
  const int c = blockIdx.y;
  const int j = (blockIdx.x * 256 + threadIdx.x) * 4;

  const int4 i4 = *(const int4*)(idx + b * TOUT + j);
  const float* __restrict__ xrow = x + ((size_t)b * CC + c) * TT;

  float4 v;
  v.x = (i4.x >= 0) ? xrow[i4.x] : 0.0f;
  v.y = (i4.y >= 0) ? xrow[i4.y] : 0.0f;
  v.z = (i4.z >= 0) ? xrow[i4.z] : 0.0f;
  v.w = (i4.w >= 0) ? xrow[i4.w] : 0.0f;

  *(float4*)(out + (((size_t)b * CC + c) * TOUT) + j) = v;

  if (c == 0) {
    float4 m;
    m.x = (v.x != 0.0f) ? 1.0f : 0.0f;
    m.y = (v.y != 0.0f) ? 1.0f : 0.0f;
    m.z = (v.z != 0.0f) ? 1.0f : 0.0f;
    m.w = (v.w != 0.0f) ? 1.0f : 0.0f;
    *(float4*)(mask + (size_t)b * TOUT + j) = m;
  }
}

extern "C" void kernel_launch(void* const* d_in, const int* in_sizes, int n_in,
                              void* d_out, int out_size, void* d_ws, size_t ws_size,
                              hipStream_t stream) {
  const float* x = (const float*)d_in[0];       // (B, C, T) f32
  const int* dur = (const int*)d_in[1];         // (B, 1, T) i32

  float* out = (float*)d_out;                   // (B, C, TOUT) f32
  float* mask = out + (size_t)BB * CC * TOUT;   // (B, 1, TOUT), written as f32 0/1

  int* idx = (int*)d_ws;                        // (B, TOUT) i32 = 1 MB

  build_idx_kernel<<<BB, TT, 0, stream>>>(dur, idx);
  gather_kernel<<<dim3(TOUT / 1024, CC, BB), 256, 0, stream>>>(x, idx, out, mask);
}

// Round 2
// 481.435 us; speedup vs baseline: 1.0276x; 1.0276x over previous
//
#include <hip/hip_runtime.h>

// LengthRegulator: B=64, C=384, T=512 -> MAX_NEW_TIME=4096
// dur[b,t] in [0,8). csum = inclusive scan. Frame t owns output positions
// [csum[t-1], csum[t]). Positions >= total are zero. Mask = (out[b,0,j] != 0).

#define BB 64
#define CC 384
#define TT 512
#define TOUT 4096
#define CBLK 8   // channels per gather block: 8 rows x 2KB = 16KB, fits L1

// Kernel 1: per-batch scan of durations + scatter of frame index into idx table.
// idx[b*TOUT + j] = t such that csum[t-1] <= j < csum[t], else -1.
__global__ __launch_bounds__(TT) void build_idx_kernel(
    const int* __restrict__ dur, int* __restrict__ idx) {
  const int b = blockIdx.x;
  const int t = threadIdx.x;

  __shared__ int s[TT];
  const int d = dur[b * TT + t];
  s[t] = d;
  __syncthreads();

  // Hillis-Steele inclusive scan over 512 elements (9 steps)
  for (int off = 1; off < TT; off <<= 1) {
    int v = (t >= off) ? s[t - off] : 0;
    __syncthreads();
    s[t] += v;
    __syncthreads();
  }

  const int end = s[t];
  const int start = end - d;

  int* __restrict__ idxb = idx + b * TOUT;
  // Fill with -1 (invalid / zero region)
  #pragma unroll
  for (int k = 0; k < TOUT / TT; ++k) idxb[t + k * TT] = -1;
  __syncthreads();

  // Scatter: segments are disjoint, at most 7 writes per thread
  for (int p = start; p < end; ++p) idxb[p] = t;
}

// Kernel 2: channel-blocked coalesced expand-gather.
// grid = (TOUT/1024, C/CBLK, B), block = 256.
// Each thread: loads int4 of indices ONCE, reuses across CBLK channels,
// emitting CBLK coalesced float4 stores (64 B j-tile per wave-lane group).
__global__ __launch_bounds__(256) void gather_kernel(
    const float* __restrict__ x, const int* __restrict__ idx,
    float* __restrict__ out, float* __restrict__ mask) {
  const int b = blockIdx.z;
  const int c0 = blockIdx.y * CBLK;
  const int j = (blockIdx.x * 256 + threadIdx.x) * 4;

  const int4 i4 = *(const int4*)(idx + b * TOUT + j);
  const bool vx = (i4.x >= 0);
  const bool vy = (i4.y >= 0);
  const bool vz = (i4.z >= 0);
  const bool vw = (i4.w >= 0);
  // clamp invalid to 0 so loads stay in-bounds; select 0.0f after
  const int ix = vx ? i4.x : 0;
  const int iy = vy ? i4.y : 0;
  const int iz = vz ? i4.z : 0;
  const int iw = vw ? i4.w : 0;

  const float* __restrict__ xb = x + ((size_t)b * CC + c0) * TT;
  float* __restrict__ ob = out + ((size_t)b * CC + c0) * TOUT + j;

  #pragma unroll
  for (int cc = 0; cc < CBLK; ++cc) {
    const float* __restrict__ xr = xb + cc * TT;
    float4 v;
    v.x = vx ? xr[ix] : 0.0f;
    v.y = vy ? xr[iy] : 0.0f;
    v.z = vz ? xr[iz] : 0.0f;
    v.w = vw ? xr[iw] : 0.0f;
    *(float4*)(ob + (size_t)cc * TOUT) = v;

    if (cc == 0 && c0 == 0) {
      float4 m;
      m.x = (v.x != 0.0f) ? 1.0f : 0.0f;
      m.y = (v.y != 0.0f) ? 1.0f : 0.0f;
      m.z = (v.z != 0.0f) ? 1.0f : 0.0f;
      m.w = (v.w != 0.0f) ? 1.0f : 0.0f;
      *(float4*)(mask + (size_t)b * TOUT + j) = m;
    }
  }
}

extern "C" void kernel_launch(void* const* d_in, const int* in_sizes, int n_in,
                              void* d_out, int out_size, void* d_ws, size_t ws_size,
                              hipStream_t stream) {
  const float* x = (const float*)d_in[0];       // (B, C, T) f32
  const int* dur = (const int*)d_in[1];         // (B, 1, T) i32

  float* out = (float*)d_out;                   // (B, C, TOUT) f32
  float* mask = out + (size_t)BB * CC * TOUT;   // (B, 1, TOUT), written as f32 0/1

  int* idx = (int*)d_ws;                        // (B, TOUT) i32 = 1 MB

  build_idx_kernel<<<BB, TT, 0, stream>>>(dur, idx);
  gather_kernel<<<dim3(TOUT / 1024, CC / CBLK, BB), 256, 0, stream>>>(x, idx, out, mask);
}

// Round 3
// 431.773 us; speedup vs baseline: 1.1458x; 1.1150x over previous
//
#include <hip/hip_runtime.h>

// LengthRegulator: B=64, C=384, T=512 -> MAX_NEW_TIME=4096
// dur[b,t] in [0,8). csum = inclusive scan. Frame t owns output positions
// [csum[t-1], csum[t]). Positions >= total are zero. Mask = (out[b,0,j] != 0).

#define BB 64
#define CC 384
#define TT 512
#define TOUT 4096
#define CB 16   // channels per gather block: 16 rows x 2KB = 32KB LDS

// Kernel 1: per-batch scan of durations + scatter of frame index into idx table.
// idx[b*TOUT + j] = t such that csum[t-1] <= j < csum[t], else -1.
__global__ __launch_bounds__(TT) void build_idx_kernel(
    const int* __restrict__ dur, int* __restrict__ idx) {
  const int b = blockIdx.x;
  const int t = threadIdx.x;

  __shared__ int s[TT];
  const int d = dur[b * TT + t];
  s[t] = d;
  __syncthreads();

  // Hillis-Steele inclusive scan over 512 elements (9 steps)
  for (int off = 1; off < TT; off <<= 1) {
    int v = (t >= off) ? s[t - off] : 0;
    __syncthreads();
    s[t] += v;
    __syncthreads();
  }

  const int end = s[t];
  const int start = end - d;

  int* __restrict__ idxb = idx + b * TOUT;
  // Fill with -1 (invalid / zero region)
  #pragma unroll
  for (int k = 0; k < TOUT / TT; ++k) idxb[t + k * TT] = -1;
  __syncthreads();

  // Scatter: segments are disjoint, at most 7 writes per thread
  for (int p = start; p < end; ++p) idxb[p] = t;
}

// Kernel 2: LDS-staged expand-gather.
// grid = (C/CB, B), block = 256. Stage 16 x-rows (32 KB) into LDS via
// coalesced float4 loads; each thread keeps its own 16 indices (4x int4,
// coalesced) in registers; gather from LDS (divergence-friendly), store
// fully-coalesced float4. Global traffic: x read exactly once, stores pure.
__global__ __launch_bounds__(256) void gather_kernel(
    const float* __restrict__ x, const int* __restrict__ idx,
    float* __restrict__ out, float* __restrict__ mask) {
  const int b = blockIdx.y;
  const int c0 = blockIdx.x * CB;
  const int tid = threadIdx.x;

  __shared__ float xs[CB * TT];  // 32 KB

  // Stage x tile: 8192 floats = 2048 float4, 8 per thread, coalesced.
  const float4* __restrict__ xb4 =
      (const float4*)(x + ((size_t)b * CC + c0) * TT);
  float4* __restrict__ xs4 = (float4*)xs;
  #pragma unroll
  for (int k = 0; k < (CB * TT / 4) / 256; ++k)
    xs4[k * 256 + tid] = xb4[k * 256 + tid];

  // Index registers: this thread's 16 output positions (4 per j-tile of 1024).
  const int4* __restrict__ ib4 = (const int4*)(idx + (size_t)b * TOUT);
  int4 I[TOUT / 1024];
  #pragma unroll
  for (int jt = 0; jt < TOUT / 1024; ++jt)
    I[jt] = ib4[jt * 256 + tid];

  __syncthreads();

  float* __restrict__ ob = out + ((size_t)b * CC + c0) * TOUT + tid * 4;

  #pragma unroll
  for (int c = 0; c < CB; ++c) {
    const float* __restrict__ xr = xs + c * TT;
    #pragma unroll
    for (int jt = 0; jt < TOUT / 1024; ++jt) {
      const int4 i4 = I[jt];
      float4 v;
      v.x = (i4.x >= 0) ? xr[i4.x] : 0.0f;
      v.y = (i4.y >= 0) ? xr[i4.y] : 0.0f;
      v.z = (i4.z >= 0) ? xr[i4.z] : 0.0f;
      v.w = (i4.w >= 0) ? xr[i4.w] : 0.0f;
      *(float4*)(ob + (size_t)c * TOUT + jt * 1024) = v;

      if (c == 0 && c0 == 0) {
        float4 m;
        m.x = (v.x != 0.0f) ? 1.0f : 0.0f;
        m.y = (v.y != 0.0f) ? 1.0f : 0.0f;
        m.z = (v.z != 0.0f) ? 1.0f : 0.0f;
        m.w = (v.w != 0.0f) ? 1.0f : 0.0f;
        *(float4*)(mask + (size_t)b * TOUT + jt * 1024 + tid * 4) = m;
      }
    }
  }
}

extern "C" void kernel_launch(void* const* d_in, const int* in_sizes, int n_in,
                              void* d_out, int out_size, void* d_ws, size_t ws_size,
                              hipStream_t stream) {
  const float* x = (const float*)d_in[0];       // (B, C, T) f32
  const int* dur = (const int*)d_in[1];         // (B, 1, T) i32

  float* out = (float*)d_out;                   // (B, C, TOUT) f32
  float* mask = out + (size_t)BB * CC * TOUT;   // (B, 1, TOUT), written as f32 0/1

  int* idx = (int*)d_ws;                        // (B, TOUT) i32 = 1 MB

  build_idx_kernel<<<BB, TT, 0, stream>>>(dur, idx);
  gather_kernel<<<dim3(CC / CB, BB), 256, 0, stream>>>(x, idx, out, mask);
}